// Round 3
// baseline (19.247 us; speedup 1.0000x reference)
//
#include <hip/hip_runtime.h>

namespace {

constexpr int IMG = 192;
constexpr int OX = 95, OY = 95;
constexpr int NPB = OX * OY;            // 9025 patches / image
constexpr int BATCH = 128;
constexpr int TPX = 16, TPY = 16;       // patch tile per workgroup
constexpr int NTX = 6, NTY = 6;         // ceil(95/16)
constexpr int TILES = NTX * NTY;        // 36
constexpr int NWG = BATCH * TILES;      // 4608 (divisible by 8)
constexpr int PR = 2 * TPX + 2;         // 34 pixel rows per tile
constexpr int PC = 2 * TPY + 2;         // 34 pixel cols
constexpr int NPIX = PR * PC;           // 1156

__device__ __forceinline__ float2 cmul(float2 a, float2 b) {
    return make_float2(a.x*b.x - a.y*b.y, a.x*b.y + a.y*b.x);
}

__global__ __launch_bounds__(256) void quanv_kernel(
    const float* __restrict__ X, const float* __restrict__ W,
    float* __restrict__ out)
{
    __shared__ __align__(16) float2 pix[NPIX];  // (sin(x/2), cos(x/2)) per pixel
    __shared__ float wc[24];                    // weight-derived constants

    // XCD-chunked swizzle: consecutive wg (same image) share an XCD L2.
    int orig = blockIdx.x;
    int wg = (orig & 7) * (NWG / 8) + (orig >> 3);

    int b  = wg / TILES;
    int t  = wg - b * TILES;
    int tx = t / NTY;
    int ty = t - tx * NTY;
    const int r0 = 32 * tx, c0 = 32 * ty;

    if (threadIdx.x == 0) {
#pragma unroll
        for (int k = 0; k < 4; ++k) {
            float sh, chh, sry, cry;
            __sincosf(0.5f * W[k], &sh, &chh);
            __sincosf(W[4 + k], &sry, &cry);
            wc[k]      = chh*chh - sh*sh;  // cos w
            wc[4 + k]  = 2.f * chh * sh;   // sin w
            wc[8 + k]  = chh;              // Eh.x  (e^{-i w/2})
            wc[12 + k] = -sh;              // Eh.y
            wc[16 + k] = 0.5f  * cry;      // Kq
            wc[20 + k] = 0.25f * sry;      // S4
        }
    }

    // ---- load phase: half-angle sincos per tile pixel, once ----
    const float* img = X + (size_t)b * (IMG * IMG);
#pragma unroll
    for (int e = threadIdx.x; e < NPIX; e += 256) {
        int r = e / PC, c = e - r * PC;
        int gr = min(r0 + r, IMG - 1);
        int gc = min(c0 + c, IMG - 1);
        float x = img[gr * IMG + gc];
        float sh, chh;
        __sincosf(0.5f * x, &sh, &chh);
        pix[e] = make_float2(sh, chh);
    }
    __syncthreads();

    // ---- compute phase: one patch per thread ----
    int lpx = threadIdx.x >> 4, lpy = threadIdx.x & 15;
    int px = tx * TPX + lpx, py = ty * TPY + lpy;
    if (px >= OX || py >= OY) return;

    // gather 16 half-angle pairs; feature f = di*4+dj
    float sh[16], ch[16];
    const float4* p4 = reinterpret_cast<const float4*>(pix);
#pragma unroll
    for (int di = 0; di < 4; ++di) {
        int base2 = ((2*lpx + di) * PC + 2*lpy) >> 1;   // 16B-aligned float4 idx
        float4 a = p4[base2], bb = p4[base2 + 1];
        sh[di*4+0] = a.x;  ch[di*4+0] = a.y;
        sh[di*4+1] = a.z;  ch[di*4+1] = a.w;
        sh[di*4+2] = bb.x; ch[di*4+2] = bb.y;
        sh[di*4+3] = bb.z; ch[di*4+3] = bb.w;
    }

    // per-qubit encoding (global phase stripped); full angle via double-angle
    float m[4];
    float2 cq[4];
#pragma unroll
    for (int q = 0; q < 3; ++q) {
        const int f = q * 5;
        float c0f = ch[f]*ch[f] - sh[f]*sh[f];
        float s0f = 2.f * sh[f] * ch[f];
        float s1 = sh[f+1], c1 = ch[f+1];
        float c2f = ch[f+2]*ch[f+2] - sh[f+2]*sh[f+2];
        float s2f = 2.f * sh[f+2] * ch[f+2];
        float s3 = sh[f+3], c3 = ch[f+3];
        float c4f = ch[f+4]*ch[f+4] - sh[f+4]*sh[f+4];
        float s4f = 2.f * sh[f+4] * ch[f+4];

        float2 u0 = make_float2(c1 - s1*c0f, -s1*s0f);
        float2 u1 = make_float2(s1 + c1*c0f,  c1*s0f);
        u1 = cmul(u1, make_float2(c2f, s2f));
        float2 n0 = make_float2(c3*u0.x - s3*u1.x, c3*u0.y - s3*u1.y);
        float2 n1 = make_float2(s3*u0.x + c3*u1.x, s3*u0.y + c3*u1.y);
        n1 = cmul(n1, make_float2(c4f, s4f));
        m[q]  = (n0.x*n0.x + n0.y*n0.y) - (n1.x*n1.x + n1.y*n1.y);
        cq[q] = make_float2(n0.x*n1.x + n0.y*n1.y, n0.x*n1.y - n0.y*n1.x);
    }
    {   // qubit 3: RZ only
        float c = ch[15]*ch[15] - sh[15]*sh[15];
        float s = 2.f * sh[15] * ch[15];
        m[3]  = 0.f;
        cq[3] = make_float2(c, s);
    }

    // a(alpha, m) = (1+cos a) + (m/2)(1-cos a) + i sin(a)(1 - m/2)
    float2 aC[4], aT[4];
#pragma unroll
    for (int j = 0; j < 4; ++j) {
        float hm = 0.5f * m[j];
        int jm = (j + 3) & 3;
        float cwj = wc[j],  swj = wc[4 + j];
        float cwm = wc[jm], swm = wc[4 + jm];
        aC[j] = make_float2((1.f + cwj) + hm * (1.f - cwj), swj * (1.f - hm));
        aT[j] = make_float2((1.f + cwm) + hm * (1.f - cwm), swm * (1.f - hm));
    }

    float ev[4];
#pragma unroll
    for (int q = 0; q < 4; ++q) {
        float2 tt = cmul(aC[(q+3)&3], aT[(q+1)&3]);
        tt = cmul(tt, make_float2(wc[8+q], wc[12+q]));
        float cross = cq[q].x * tt.x - cq[q].y * tt.y;
        ev[q] = wc[16+q] * m[q] - wc[20+q] * cross;
    }

    reinterpret_cast<float4*>(out)[b * NPB + px * OY + py] =
        make_float4(ev[0], ev[1], ev[2], ev[3]);
}

} // namespace

extern "C" void kernel_launch(void* const* d_in, const int* in_sizes, int n_in,
                              void* d_out, int out_size, void* d_ws, size_t ws_size,
                              hipStream_t stream) {
    const float* X = (const float*)d_in[0];
    const float* W = (const float*)d_in[1];
    float* out = (float*)d_out;
    quanv_kernel<<<NWG, 256, 0, stream>>>(X, W, out);
}

// Round 4
// 16.803 us; speedup vs baseline: 1.1455x; 1.1455x over previous
//
#include <hip/hip_runtime.h>

namespace {

constexpr int IMG = 192;
constexpr int OX = 95, OY = 95;
constexpr int NPB = OX * OY;          // 9025 patches / image
constexpr int BATCH = 128;
constexpr int JP = 48;                // column pairs per row (py = 2j, 2j+1)
constexpr int PERIMG = OX * JP;       // 4560 threads / image
constexpr int TOTAL = BATCH * PERIMG; // 583,680
constexpr int NWG = TOTAL / 256;      // 2280 (divisible by 8)
constexpr int CHUNK = NWG / 8;        // 285

__device__ __forceinline__ float2 cmul(float2 a, float2 b) {
    return make_float2(a.x*b.x - a.y*b.y, a.x*b.y + a.y*b.x);
}

// One qubit: RZ(t0) RY(t1) RZ(t2) RY(t3) RZ(t4) on (1,1)/sqrt2 (phase-stripped).
// Inputs are HALF-angle (sin,cos); full angles derived by double-angle.
__device__ __forceinline__ void qubit_chain(
    float s0, float c0, float s1, float c1, float s2, float c2,
    float s3, float c3, float s4, float c4,
    float& m, float2& cq)
{
    float C0 = c0*c0 - s0*s0, S0 = 2.f*s0*c0;
    float C2 = c2*c2 - s2*s2, S2 = 2.f*s2*c2;
    float C4 = c4*c4 - s4*s4, S4f = 2.f*s4*c4;
    float2 u0 = make_float2(c1 - s1*C0, -s1*S0);
    float2 u1 = make_float2(s1 + c1*C0,  c1*S0);
    u1 = cmul(u1, make_float2(C2, S2));
    float2 n0 = make_float2(c3*u0.x - s3*u1.x, c3*u0.y - s3*u1.y);
    float2 n1 = make_float2(s3*u0.x + c3*u1.x, s3*u0.y + c3*u1.y);
    n1 = cmul(n1, make_float2(C4, S4f));
    m  = (n0.x*n0.x + n0.y*n0.y) - (n1.x*n1.x + n1.y*n1.y);
    cq = make_float2(n0.x*n1.x + n0.y*n1.y, n0.x*n1.y - n0.y*n1.x);
}

__device__ __forceinline__ float4 patch_ev(
    const float sh[4][6], const float ch[4][6], int o,
    const float cw[4], const float sw[4], const float ehx[4], const float ehy[4],
    const float Kq[4], const float S4v[4])
{
    float m[4]; float2 cq[4];
    qubit_chain(sh[0][o+0],ch[0][o+0], sh[0][o+1],ch[0][o+1], sh[0][o+2],ch[0][o+2],
                sh[0][o+3],ch[0][o+3], sh[1][o+0],ch[1][o+0], m[0], cq[0]);
    qubit_chain(sh[1][o+1],ch[1][o+1], sh[1][o+2],ch[1][o+2], sh[1][o+3],ch[1][o+3],
                sh[2][o+0],ch[2][o+0], sh[2][o+1],ch[2][o+1], m[1], cq[1]);
    qubit_chain(sh[2][o+2],ch[2][o+2], sh[2][o+3],ch[2][o+3], sh[3][o+0],ch[3][o+0],
                sh[3][o+1],ch[3][o+1], sh[3][o+2],ch[3][o+2], m[2], cq[2]);
    {   // qubit 3: RZ(f15) only -> m = 0 exactly
        float s = sh[3][o+3], c = ch[3][o+3];
        m[3]  = 0.f;
        cq[3] = make_float2(c*c - s*s, 2.f*s*c);
    }

    float ev[4];
#pragma unroll
    for (int q = 0; q < 4; ++q) {
        int jm = (q + 3) & 3, jp = (q + 1) & 3;
        float hmC = 0.5f * m[jm];
        float2 aC = make_float2((1.f + cw[jm]) + hmC * (1.f - cw[jm]),
                                sw[jm] * (1.f - hmC));
        float hmT = 0.5f * m[jp];
        float2 aT = make_float2((1.f + cw[q]) + hmT * (1.f - cw[q]),
                                sw[q] * (1.f - hmT));
        float2 t = cmul(aC, aT);
        t = cmul(t, make_float2(ehx[q], ehy[q]));
        ev[q] = Kq[q] * m[q] - S4v[q] * (cq[q].x * t.x - cq[q].y * t.y);
    }
    return make_float4(ev[0], ev[1], ev[2], ev[3]);
}

__global__ __launch_bounds__(256) void quanv_kernel(
    const float* __restrict__ X, const float* __restrict__ W,
    float* __restrict__ out)
{
    int orig = blockIdx.x;
    int wg = (orig & 7) * CHUNK + (orig >> 3);   // XCD-chunked swizzle
    int tid = wg * 256 + threadIdx.x;
    int b  = tid / PERIMG;
    int r  = tid - b * PERIMG;
    int px = r / JP;
    int j  = r - px * JP;
    const bool hasB = (j < JP - 1);              // patch b: py = 2j+1 (j=47 -> 95, invalid)

    const float* img = X + (size_t)b * (IMG*IMG) + (2*px) * IMG + 4*j;
    const int c45 = hasB ? 4 : 0;                // safe dummy addr for j==47

    // load 4 rows x 6 cols (float4 + float2, both 16B/8B aligned)
    float raw[4][6];
#pragma unroll
    for (int di = 0; di < 4; ++di) {
        const float* rp = img + di * IMG;
        float4 v  = *reinterpret_cast<const float4*>(rp);
        float2 w2 = *reinterpret_cast<const float2*>(rp + c45);
        raw[di][0] = v.x; raw[di][1] = v.y; raw[di][2] = v.z; raw[di][3] = v.w;
        raw[di][4] = w2.x; raw[di][5] = w2.y;
    }

    // weight-derived constants (uniform; amortized over 2 patches)
    float cw[4], sw[4], ehx[4], ehy[4], Kq[4], S4v[4];
#pragma unroll
    for (int k = 0; k < 4; ++k) {
        float shh, chh, sry, cry;
        __sincosf(0.5f * W[k], &shh, &chh);
        __sincosf(W[4 + k], &sry, &cry);
        cw[k]  = chh*chh - shh*shh;
        sw[k]  = 2.f * chh * shh;
        ehx[k] = chh;
        ehy[k] = -shh;
        Kq[k]  = 0.5f  * cry;
        S4v[k] = 0.25f * sry;
    }

    // half-angle sincos for all 24 pixels
    float sh[4][6], ch[4][6];
#pragma unroll
    for (int di = 0; di < 4; ++di)
#pragma unroll
        for (int cc = 0; cc < 6; ++cc)
            __sincosf(0.5f * raw[di][cc], &sh[di][cc], &ch[di][cc]);

    float4 evA = patch_ev(sh, ch, 0, cw, sw, ehx, ehy, Kq, S4v);
    float4 evB = patch_ev(sh, ch, 2, cw, sw, ehx, ehy, Kq, S4v);

    float4* o4 = reinterpret_cast<float4*>(out) + (size_t)b * NPB + px * OY + 2*j;
    o4[0] = evA;
    if (hasB) o4[1] = evB;
}

} // namespace

extern "C" void kernel_launch(void* const* d_in, const int* in_sizes, int n_in,
                              void* d_out, int out_size, void* d_ws, size_t ws_size,
                              hipStream_t stream) {
    const float* X = (const float*)d_in[0];
    const float* W = (const float*)d_in[1];
    float* out = (float*)d_out;
    quanv_kernel<<<NWG, 256, 0, stream>>>(X, W, out);
}